// Round 1
// baseline (754.172 us; speedup 1.0000x reference)
//
#include <hip/hip_runtime.h>
#include <hip/hip_bf16.h>

// ---------------- problem constants ----------------
#define TPAD   65656    // t_padded
#define TOUT   65536
#define CCH    384      // channels
#define NROWS  768      // SIZE * C
#define HOP    392
#define NB     168
#define BS     512      // fft block size
#define KPAD   416      // 392 padded to multiple of 32
#define M1     129024   // NROWS * NB
#define M2     131072   // 2 * TOUT

typedef __attribute__((ext_vector_type(8))) _Float16 f16x8;
typedef __attribute__((ext_vector_type(4))) _Float16 f16x4;
typedef __attribute__((ext_vector_type(4))) float    f32x4;

__device__ __forceinline__ void gload_lds16(const void* g, void* l) {
    __builtin_amdgcn_global_load_lds(
        (__attribute__((address_space(1))) void*)g,
        (__attribute__((address_space(3))) void*)l, 16, 0, 0);
}

// ---------------- h = irfft_backward(kernel_fft, 512) ----------------
__global__ void build_h_kernel(const float* __restrict__ kfft, float* __restrict__ h) {
    __shared__ float Ks[257];
    int j = threadIdx.x;          // 0..511
    if (j < 257) Ks[j] = kfft[j];
    __syncthreads();
    float acc = Ks[0] + ((j & 1) ? -Ks[256] : Ks[256]);
    const float w0 = 6.2831853071795864769f / 512.0f;
    for (int f = 1; f < 256; ++f) {
        int m = (f * j) & 511;            // exact integer phase reduction
        acc += 2.0f * Ks[f] * cosf(w0 * (float)m);
    }
    h[j] = acc * (1.0f / 512.0f);
}

// ---------------- Ht[j][i] = h[(j-i) mod 512], i<392 else 0 ----------------
__global__ void build_ht_kernel(const float* __restrict__ h, _Float16* __restrict__ Ht) {
    int j = blockIdx.x;                               // 0..511
    int i = blockIdx.y * 256 + threadIdx.x;           // 0..511
    if (i >= KPAD) return;
    float v = (i < HOP) ? h[(j - i) & 511] : 0.0f;
    Ht[j * KPAD + i] = (_Float16)v;
}

// ---------------- spT[d][c] = std[c] * vt[c][d] ----------------
__global__ void build_spt_kernel(const float* __restrict__ sstd, const float* __restrict__ vt,
                                 _Float16* __restrict__ spT) {
    int d = blockIdx.x;      // 0..383
    int c = threadIdx.x;     // 0..383
    spT[d * CCH + c] = (_Float16)(sstd[c] * vt[c * CCH + d]);
}

// ---------------- stage 1: yb[rb][j] = sum_i x[rb][i] * Ht[j][i] ----------------
// A: noise fp32 (cast-staged), M1 x KPAD logical. B: Ht f16 (512 x 416). C: yb f16.
__global__ __launch_bounds__(256) void gemm1_kernel(const float* __restrict__ noise,
                                                    const _Float16* __restrict__ Ht,
                                                    _Float16* __restrict__ yb) {
    __shared__ __align__(16) _Float16 As[128 * 32];
    __shared__ __align__(16) _Float16 Bs[128 * 32];
    const int tid  = threadIdx.x;
    const int w    = tid >> 6, lane = tid & 63;
    const int quad = lane >> 4, lm = lane & 15;
    const int wm   = w >> 1, wn = w & 1;
    const int m0   = blockIdx.y * 128;
    const int n0   = blockIdx.x * 128;

    // A-staging row assignment (constant across k-tiles)
    const float* abase[4];
    int arow[4], alim[4];
#pragma unroll
    for (int q = 0; q < 4; ++q) {
        int f = q * 256 + tid;
        int row = f >> 3;
        arow[q] = row;
        int rb = m0 + row;
        int r  = rb / NB;
        int b  = rb - r * NB;
        abase[q] = noise + r * TPAD + b * HOP;
        alim[q]  = (b == NB - 1) ? (TPAD - (NB - 1) * HOP) : HOP;   // 192 or 392
    }

    f32x4 acc[4][4] = {};

    for (int kt = 0; kt < KPAD / 32; ++kt) {
        const int k0 = kt * 32;
        // B tile: global_load_lds, 2 rounds x 256 lanes x 16B = 8 KiB
#pragma unroll
        for (int ro = 0; ro < 2; ++ro) {
            int gidx = ro * 256 + tid;
            int row  = gidx >> 2;
            int col  = (gidx & 3) * 8;
            gload_lds16(Ht + (n0 + row) * KPAD + k0 + col,
                        Bs + (ro * 256 + (tid & ~63)) * 8);
        }
        // A tile: manual fp32 load + cast + ds_write
#pragma unroll
        for (int q = 0; q < 4; ++q) {
            int f  = q * 256 + tid;
            int c4 = (f & 7) * 4;
            int i  = k0 + c4;
            f32x4 v = {0.f, 0.f, 0.f, 0.f};
            if (i < alim[q]) v = *(const f32x4*)(abase[q] + i);
            f16x4 hv = __builtin_convertvector(v, f16x4);
            *(f16x4*)(As + arow[q] * 32 + c4) = hv;
        }
        __syncthreads();

        f16x8 a[4], b[4];
#pragma unroll
        for (int mi = 0; mi < 4; ++mi)
            a[mi] = *(const f16x8*)(As + (wm * 64 + mi * 16 + lm) * 32 + quad * 8);
#pragma unroll
        for (int ni = 0; ni < 4; ++ni)
            b[ni] = *(const f16x8*)(Bs + (wn * 64 + ni * 16 + lm) * 32 + quad * 8);
#pragma unroll
        for (int mi = 0; mi < 4; ++mi)
#pragma unroll
            for (int ni = 0; ni < 4; ++ni)
                acc[mi][ni] = __builtin_amdgcn_mfma_f32_16x16x32_f16(a[mi], b[ni], acc[mi][ni], 0, 0, 0);
        __syncthreads();
    }

    // epilogue: f16 stores, C/D layout col=lane&15, row=quad*4+e
#pragma unroll
    for (int mi = 0; mi < 4; ++mi)
#pragma unroll
        for (int e = 0; e < 4; ++e) {
            int row = m0 + wm * 64 + mi * 16 + quad * 4 + e;
            _Float16* dst = yb + row * BS + n0 + wn * 64 + lm;
#pragma unroll
            for (int ni = 0; ni < 4; ++ni)
                dst[ni * 16] = (_Float16)acc[mi][ni][e];
        }
}

// ---------------- overlap-add + transpose: Yt[n][t][c] ----------------
__global__ __launch_bounds__(256) void oa_kernel(const _Float16* __restrict__ yb,
                                                 _Float16* __restrict__ Yt) {
    __shared__ float Ls[32][33];
    const int tx = threadIdx.x & 31, ty = threadIdx.x >> 5;   // 32 x 8
    const int t0 = blockIdx.x * 32, c0 = blockIdx.y * 32, n = blockIdx.z;
#pragma unroll
    for (int s = 0; s < 4; ++s) {
        int cc = ty + s * 8;
        int r  = n * CCH + c0 + cc;
        int g  = t0 + tx + 120;
        int b  = g / HOP;
        int j  = g - b * HOP;
        int idx = (r * NB + b) * BS + j;
        float v = (float)yb[idx];
        if (j < 120) v += (float)yb[idx - 120];   // = yb[r, b-1, j+392]
        Ls[cc][tx] = v;
    }
    __syncthreads();
#pragma unroll
    for (int s = 0; s < 4; ++s) {
        int tt = ty + s * 8;
        Yt[(n * TOUT + t0 + tt) * CCH + c0 + tx] = (_Float16)Ls[tx][tt];
    }
}

// ---------------- stage 2: out[(n,t)][d] = sum_c Yt[(n,t)][c] * spT[d][c] ----------------
__global__ __launch_bounds__(256) void gemm2_kernel(const _Float16* __restrict__ Yt,
                                                    const _Float16* __restrict__ spT,
                                                    float* __restrict__ outp) {
    __shared__ __align__(16) _Float16 As[128 * 32];
    __shared__ __align__(16) _Float16 Bs[128 * 32];
    const int tid  = threadIdx.x;
    const int w    = tid >> 6, lane = tid & 63;
    const int quad = lane >> 4, lm = lane & 15;
    const int wm   = w >> 1, wn = w & 1;
    const int m0   = blockIdx.y * 128;
    const int n0   = blockIdx.x * 128;

    f32x4 acc[4][4] = {};

    for (int kt = 0; kt < CCH / 32; ++kt) {
        const int k0 = kt * 32;
#pragma unroll
        for (int ro = 0; ro < 2; ++ro) {
            int gidx = ro * 256 + tid;
            int row  = gidx >> 2;
            int col  = (gidx & 3) * 8;
            gload_lds16(Yt + (m0 + row) * CCH + k0 + col,
                        As + (ro * 256 + (tid & ~63)) * 8);
            gload_lds16(spT + (n0 + row) * CCH + k0 + col,
                        Bs + (ro * 256 + (tid & ~63)) * 8);
        }
        __syncthreads();

        f16x8 a[4], b[4];
#pragma unroll
        for (int mi = 0; mi < 4; ++mi)
            a[mi] = *(const f16x8*)(As + (wm * 64 + mi * 16 + lm) * 32 + quad * 8);
#pragma unroll
        for (int ni = 0; ni < 4; ++ni)
            b[ni] = *(const f16x8*)(Bs + (wn * 64 + ni * 16 + lm) * 32 + quad * 8);
#pragma unroll
        for (int mi = 0; mi < 4; ++mi)
#pragma unroll
            for (int ni = 0; ni < 4; ++ni)
                acc[mi][ni] = __builtin_amdgcn_mfma_f32_16x16x32_f16(a[mi], b[ni], acc[mi][ni], 0, 0, 0);
        __syncthreads();
    }

#pragma unroll
    for (int mi = 0; mi < 4; ++mi)
#pragma unroll
        for (int e = 0; e < 4; ++e) {
            int row = m0 + wm * 64 + mi * 16 + quad * 4 + e;
            float* dst = outp + row * CCH + n0 + wn * 64 + lm;
#pragma unroll
            for (int ni = 0; ni < 4; ++ni)
                dst[ni * 16] = acc[mi][ni][e];
        }
}

// ---------------- launch ----------------
extern "C" void kernel_launch(void* const* d_in, const int* in_sizes, int n_in,
                              void* d_out, int out_size, void* d_ws, size_t ws_size,
                              hipStream_t stream) {
    const float* noise = (const float*)d_in[0];
    const float* sstd  = (const float*)d_in[1];
    const float* vt    = (const float*)d_in[2];
    const float* kfft  = (const float*)d_in[3];
    float* out = (float*)d_out;

    char* ws = (char*)d_ws;
    // ws layout (16B-aligned):
    float*    h   = (float*)ws;                              // 2048 B
    _Float16* Ht  = (_Float16*)(ws + 2048);                  // 512*416*2  = 425984
    _Float16* spT = (_Float16*)(ws + 428032);                // 384*384*2  = 294912
    _Float16* yb  = (_Float16*)(ws + 722944);                // M1*512*2   = 132120576
    _Float16* Yt  = (_Float16*)(ws + 132843520);             // M2*384*2   = 100663296
    // peak ws usage = 233,506,816 bytes

    build_h_kernel  <<<1, 512, 0, stream>>>(kfft, h);
    build_ht_kernel <<<dim3(512, 2), 256, 0, stream>>>(h, Ht);
    build_spt_kernel<<<CCH, CCH, 0, stream>>>(sstd, vt, spT);

    gemm1_kernel<<<dim3(BS / 128, M1 / 128), 256, 0, stream>>>(noise, Ht, yb);
    oa_kernel   <<<dim3(TOUT / 32, CCH / 32, 2), 256, 0, stream>>>(yb, Yt);
    gemm2_kernel<<<dim3(CCH / 128, M2 / 128), 256, 0, stream>>>(Yt, spT, out);
}

// Round 2
// 668.908 us; speedup vs baseline: 1.1275x; 1.1275x over previous
//
#include <hip/hip_runtime.h>
#include <hip/hip_bf16.h>

// ---------------- problem constants ----------------
#define TPAD   65656    // t_padded
#define TOUT   65536
#define CCH    384      // channels
#define NROWS  768      // SIZE * C
#define HOP    392
#define NB     168
#define BS     512      // fft block size
#define KPAD   416      // 392 padded to multiple of 32
#define M1     129024   // NROWS * NB
#define M2     131072   // 2 * TOUT

typedef __attribute__((ext_vector_type(8))) _Float16 f16x8;
typedef __attribute__((ext_vector_type(4))) _Float16 f16x4;
typedef __attribute__((ext_vector_type(4))) float    f32x4;
typedef __attribute__((ext_vector_type(8))) float    f32x8;

__device__ __forceinline__ void gload_lds16(const void* g, void* l) {
    __builtin_amdgcn_global_load_lds(
        (__attribute__((address_space(1))) void*)g,
        (__attribute__((address_space(3))) void*)l, 16, 0, 0);
}

// ---------------- h = irfft_backward(kernel_fft, 512) ----------------
__global__ void build_h_kernel(const float* __restrict__ kfft, float* __restrict__ h) {
    __shared__ float Ks[257];
    int j = threadIdx.x;          // 0..511
    if (j < 257) Ks[j] = kfft[j];
    __syncthreads();
    float acc = Ks[0] + ((j & 1) ? -Ks[256] : Ks[256]);
    const float w0 = 6.2831853071795864769f / 512.0f;
    for (int f = 1; f < 256; ++f) {
        int m = (f * j) & 511;            // exact integer phase reduction
        acc += 2.0f * Ks[f] * cosf(w0 * (float)m);
    }
    h[j] = acc * (1.0f / 512.0f);
}

// ---------------- Ht[j][i] = h[(j-i) mod 512], i<392 else 0 ----------------
__global__ void build_ht_kernel(const float* __restrict__ h, _Float16* __restrict__ Ht) {
    int j = blockIdx.x;                               // 0..511
    int i = blockIdx.y * 256 + threadIdx.x;           // 0..511
    if (i >= KPAD) return;
    float v = (i < HOP) ? h[(j - i) & 511] : 0.0f;
    Ht[j * KPAD + i] = (_Float16)v;
}

// ---------------- spT[d][c] = std[c] * vt[c][d] ----------------
__global__ void build_spt_kernel(const float* __restrict__ sstd, const float* __restrict__ vt,
                                 _Float16* __restrict__ spT) {
    int d = blockIdx.x;      // 0..383
    int c = threadIdx.x;     // 0..383
    spT[d * CCH + c] = (_Float16)(sstd[c] * vt[c * CCH + d]);
}

// ---------------- cast/pack: A16[row][i] = f16(noise chunk), zero-padded ----------------
// row -> (r = row/NB, b = row%NB); cols 0..391 from noise[r][b*392 + i], 392..415 zero.
// Chunk limits (392, and 192 for b=167) are multiples of 8, so every 8-wide segment
// is either fully valid or fully zero.
__global__ __launch_bounds__(256) void cast_kernel(const float* __restrict__ noise,
                                                   _Float16* __restrict__ A16) {
    int gid = blockIdx.x * 256 + threadIdx.x;    // 0 .. M1*52-1
    int row = gid / 52;
    int seg = gid - row * 52;
    int i0  = seg * 8;
    int r   = row / NB;
    int b   = row - r * NB;
    int lim = (b == NB - 1) ? (TPAD - (NB - 1) * HOP) : HOP;   // 192 or 392
    f16x8 o = {};
    if (i0 + 8 <= lim) {
        const float* src = noise + r * TPAD + b * HOP + i0;
        f32x4 v0 = *(const f32x4*)src;
        f32x4 v1 = *(const f32x4*)(src + 4);
        f32x8 v = {v0.x, v0.y, v0.z, v0.w, v1.x, v1.y, v1.z, v1.w};
        o = __builtin_convertvector(v, f16x8);
    }
    *(f16x8*)(A16 + row * KPAD + i0) = o;
}

// ---------------- stage 1: yb[rb][j] = sum_i A16[rb][i] * Ht[j][i] ----------------
// Pure m97 structure: both tiles staged via global_load_lds width=16.
__global__ __launch_bounds__(256) void gemm1_kernel(const _Float16* __restrict__ A16,
                                                    const _Float16* __restrict__ Ht,
                                                    _Float16* __restrict__ yb) {
    __shared__ __align__(16) _Float16 As[128 * 32];
    __shared__ __align__(16) _Float16 Bs[128 * 32];
    const int tid  = threadIdx.x;
    const int w    = tid >> 6, lane = tid & 63;
    const int quad = lane >> 4, lm = lane & 15;
    const int wm   = w >> 1, wn = w & 1;
    const int m0   = blockIdx.y * 128;
    const int n0   = blockIdx.x * 128;

    f32x4 acc[4][4] = {};

    for (int kt = 0; kt < KPAD / 32; ++kt) {
        const int k0 = kt * 32;
#pragma unroll
        for (int ro = 0; ro < 2; ++ro) {
            int gidx = ro * 256 + tid;
            int row  = gidx >> 2;
            int col  = (gidx & 3) * 8;
            gload_lds16(A16 + (size_t)(m0 + row) * KPAD + k0 + col,
                        As + (ro * 256 + (tid & ~63)) * 8);
            gload_lds16(Ht + (n0 + row) * KPAD + k0 + col,
                        Bs + (ro * 256 + (tid & ~63)) * 8);
        }
        __syncthreads();

        f16x8 a[4], b[4];
#pragma unroll
        for (int mi = 0; mi < 4; ++mi)
            a[mi] = *(const f16x8*)(As + (wm * 64 + mi * 16 + lm) * 32 + quad * 8);
#pragma unroll
        for (int ni = 0; ni < 4; ++ni)
            b[ni] = *(const f16x8*)(Bs + (wn * 64 + ni * 16 + lm) * 32 + quad * 8);
#pragma unroll
        for (int mi = 0; mi < 4; ++mi)
#pragma unroll
            for (int ni = 0; ni < 4; ++ni)
                acc[mi][ni] = __builtin_amdgcn_mfma_f32_16x16x32_f16(a[mi], b[ni], acc[mi][ni], 0, 0, 0);
        __syncthreads();
    }

    // epilogue: f16 stores, C/D layout col=lane&15, row=quad*4+e
#pragma unroll
    for (int mi = 0; mi < 4; ++mi)
#pragma unroll
        for (int e = 0; e < 4; ++e) {
            int row = m0 + wm * 64 + mi * 16 + quad * 4 + e;
            _Float16* dst = yb + (size_t)row * BS + n0 + wn * 64 + lm;
#pragma unroll
            for (int ni = 0; ni < 4; ++ni)
                dst[ni * 16] = (_Float16)acc[mi][ni][e];
        }
}

// ---------------- overlap-add + transpose: Yt[n][t][c] ----------------
__global__ __launch_bounds__(256) void oa_kernel(const _Float16* __restrict__ yb,
                                                 _Float16* __restrict__ Yt) {
    __shared__ float Ls[32][33];
    const int tx = threadIdx.x & 31, ty = threadIdx.x >> 5;   // 32 x 8
    const int t0 = blockIdx.x * 32, c0 = blockIdx.y * 32, n = blockIdx.z;
#pragma unroll
    for (int s = 0; s < 4; ++s) {
        int cc = ty + s * 8;
        int r  = n * CCH + c0 + cc;
        int g  = t0 + tx + 120;
        int b  = g / HOP;
        int j  = g - b * HOP;
        int idx = (r * NB + b) * BS + j;
        float v = (float)yb[idx];
        if (j < 120) v += (float)yb[idx - 120];   // = yb[r, b-1, j+392]
        Ls[cc][tx] = v;
    }
    __syncthreads();
#pragma unroll
    for (int s = 0; s < 4; ++s) {
        int tt = ty + s * 8;
        Yt[((size_t)n * TOUT + t0 + tt) * CCH + c0 + tx] = (_Float16)Ls[tx][tt];
    }
}

// ---------------- stage 2: out[(n,t)][d] = sum_c Yt[(n,t)][c] * spT[d][c] ----------------
__global__ __launch_bounds__(256) void gemm2_kernel(const _Float16* __restrict__ Yt,
                                                    const _Float16* __restrict__ spT,
                                                    float* __restrict__ outp) {
    __shared__ __align__(16) _Float16 As[128 * 32];
    __shared__ __align__(16) _Float16 Bs[128 * 32];
    const int tid  = threadIdx.x;
    const int w    = tid >> 6, lane = tid & 63;
    const int quad = lane >> 4, lm = lane & 15;
    const int wm   = w >> 1, wn = w & 1;
    const int m0   = blockIdx.y * 128;
    const int n0   = blockIdx.x * 128;

    f32x4 acc[4][4] = {};

    for (int kt = 0; kt < CCH / 32; ++kt) {
        const int k0 = kt * 32;
#pragma unroll
        for (int ro = 0; ro < 2; ++ro) {
            int gidx = ro * 256 + tid;
            int row  = gidx >> 2;
            int col  = (gidx & 3) * 8;
            gload_lds16(Yt + (size_t)(m0 + row) * CCH + k0 + col,
                        As + (ro * 256 + (tid & ~63)) * 8);
            gload_lds16(spT + (n0 + row) * CCH + k0 + col,
                        Bs + (ro * 256 + (tid & ~63)) * 8);
        }
        __syncthreads();

        f16x8 a[4], b[4];
#pragma unroll
        for (int mi = 0; mi < 4; ++mi)
            a[mi] = *(const f16x8*)(As + (wm * 64 + mi * 16 + lm) * 32 + quad * 8);
#pragma unroll
        for (int ni = 0; ni < 4; ++ni)
            b[ni] = *(const f16x8*)(Bs + (wn * 64 + ni * 16 + lm) * 32 + quad * 8);
#pragma unroll
        for (int mi = 0; mi < 4; ++mi)
#pragma unroll
            for (int ni = 0; ni < 4; ++ni)
                acc[mi][ni] = __builtin_amdgcn_mfma_f32_16x16x32_f16(a[mi], b[ni], acc[mi][ni], 0, 0, 0);
        __syncthreads();
    }

#pragma unroll
    for (int mi = 0; mi < 4; ++mi)
#pragma unroll
        for (int e = 0; e < 4; ++e) {
            int row = m0 + wm * 64 + mi * 16 + quad * 4 + e;
            float* dst = outp + (size_t)row * CCH + n0 + wn * 64 + lm;
#pragma unroll
            for (int ni = 0; ni < 4; ++ni)
                dst[ni * 16] = acc[mi][ni][e];
        }
}

// ---------------- launch ----------------
extern "C" void kernel_launch(void* const* d_in, const int* in_sizes, int n_in,
                              void* d_out, int out_size, void* d_ws, size_t ws_size,
                              hipStream_t stream) {
    const float* noise = (const float*)d_in[0];
    const float* sstd  = (const float*)d_in[1];
    const float* vt    = (const float*)d_in[2];
    const float* kfft  = (const float*)d_in[3];
    float* out = (float*)d_out;

    char* ws = (char*)d_ws;
    // ws layout (16B-aligned):
    float*    h   = (float*)ws;                              // 2048 B
    _Float16* Ht  = (_Float16*)(ws + 2048);                  // 512*416*2  = 425984
    _Float16* spT = (_Float16*)(ws + 428032);                // 384*384*2  = 294912
    _Float16* yb  = (_Float16*)(ws + 722944);                // M1*512*2   = 132120576
    _Float16* Yt  = (_Float16*)(ws + 132843520);             // M2*384*2   = 100663296
    _Float16* A16 = (_Float16*)(ws + 233506816);             // M1*416*2   = 107347968
    // peak ws usage = 340,854,784 bytes

    build_h_kernel  <<<1, 512, 0, stream>>>(kfft, h);
    build_ht_kernel <<<dim3(512, 2), 256, 0, stream>>>(h, Ht);
    build_spt_kernel<<<CCH, CCH, 0, stream>>>(sstd, vt, spT);

    cast_kernel <<<M1 * 52 / 256, 256, 0, stream>>>(noise, A16);
    gemm1_kernel<<<dim3(BS / 128, M1 / 128), 256, 0, stream>>>(A16, Ht, yb);
    oa_kernel   <<<dim3(TOUT / 32, CCH / 32, 2), 256, 0, stream>>>(yb, Yt);
    gemm2_kernel<<<dim3(CCH / 128, M2 / 128), 256, 0, stream>>>(Yt, spT, out);
}